// Round 6
// baseline (244.635 us; speedup 1.0000x reference)
//
#include <hip/hip_runtime.h>
#include <stdint.h>

#define D_FEAT 128
#define H1 18
#define H2 32
#define EPS 1e-8f

typedef float f32x4 __attribute__((ext_vector_type(4)));

__device__ __forceinline__ uint32_t f32_to_bf16_rne(float f) {
    uint32_t u = __float_as_uint(f);
    return (u + 0x7fffu + ((u >> 16) & 1u)) >> 16;
}
__device__ __forceinline__ float bf16lo(uint32_t v) { return __uint_as_float(v << 16); }
__device__ __forceinline__ float bf16hi(uint32_t v) { return __uint_as_float(v & 0xffff0000u); }

__device__ __forceinline__ float dot8(uint4 s, uint4 t) {
    float d;
    d  = bf16lo(s.x) * bf16lo(t.x);
    d  = fmaf(bf16hi(s.x), bf16hi(t.x), d);
    d  = fmaf(bf16lo(s.y), bf16lo(t.y), d);
    d  = fmaf(bf16hi(s.y), bf16hi(t.y), d);
    d  = fmaf(bf16lo(s.z), bf16lo(t.z), d);
    d  = fmaf(bf16hi(s.z), bf16hi(t.z), d);
    d  = fmaf(bf16lo(s.w), bf16lo(t.w), d);
    d  = fmaf(bf16hi(s.w), bf16hi(t.w), d);
    return d;
}

// ---------- prep: x[f32,N,128] -> NORMALIZED packed bf16 [N,32 uint2] ----------
// nt load on x only: streamed exactly once, keep it from evicting xb.
__global__ __launch_bounds__(256) void prep_kernel(
    const float* __restrict__ x,
    uint2* __restrict__ xb,
    int n_nodes)
{
    const int lane = threadIdx.x & 63;
    const int sub = lane & 31;
    const int half = lane >> 5;
    const int wavesPerBlock = blockDim.x >> 6;
    const long long wv = (long long)blockIdx.x * wavesPerBlock + (threadIdx.x >> 6);
    const int node = (int)(2 * wv + half);
    if (node >= n_nodes) return;

    const f32x4 v = __builtin_nontemporal_load(
        reinterpret_cast<const f32x4*>(x + (size_t)node * D_FEAT) + sub);
    float ss = v[0] * v[0] + v[1] * v[1] + v[2] * v[2] + v[3] * v[3];
    #pragma unroll
    for (int m = 16; m >= 1; m >>= 1) ss += __shfl_xor(ss, m);
    const float r = 1.0f / fmaxf(sqrtf(ss), EPS);
    uint2 p;
    p.x = (f32_to_bf16_rne(v[1] * r) << 16) | f32_to_bf16_rne(v[0] * r);
    p.y = (f32_to_bf16_rne(v[3] * r) << 16) | f32_to_bf16_rne(v[2] * r);
    xb[(size_t)node * 32 + sub] = p;
}

// ---------- main: work-queue of 64-edge bursts, index prefetch ----------
__global__ __launch_bounds__(256) void edge_kernel(
    const uint4* __restrict__ xb,       // [N][16] (8 bf16 per uint4)
    const int* __restrict__ edge_index, // [2, E]
    const float* __restrict__ edge_attr,
    const float* __restrict__ W1, const float* __restrict__ b1,
    const float* __restrict__ W2, const float* __restrict__ b2,
    float* __restrict__ out, int n_edges,
    unsigned int* __restrict__ counter)
{
    __shared__ int sIdx[4][2][64];
    __shared__ int tIdx[4][2][64];
    __shared__ float dotb[4][64];

    const int lane = threadIdx.x & 63;
    const int w = threadIdx.x >> 6;
    const int g = lane >> 4;
    const int k = lane & 15;
    const long long nBursts = ((long long)n_edges + 63) >> 6;

    // wave-level burst grab
    #define GRAB(DST) {                                                   \
        int _b = 0;                                                       \
        if (lane == 0) _b = (int)atomicAdd(counter, 1u);                  \
        DST = __shfl(_b, 0);                                              \
    }

    long long cur;
    GRAB(cur)
    if (cur >= nBursts) return;

    // stage indices + attr for cur into buf 0
    int buf = 0;
    f32x4 attrCur = (f32x4)0.f;
    {
        const long long e = (cur << 6) + lane;
        int sL = 0, tL = 0;
        if (e < (long long)n_edges) {
            sL = edge_index[e];
            tL = edge_index[(long long)n_edges + e];
            attrCur = reinterpret_cast<const f32x4*>(edge_attr)[e];
        }
        sIdx[w][0][lane] = sL;
        tIdx[w][0][lane] = tL;
    }

    for (;;) {
        const long long e = (cur << 6) + lane;
        const bool act = e < (long long)n_edges;

        uint4 sA[4], tA[4], sB[4], tB[4];

        #define LOADB(BS, BT, BASE)                                       \
            _Pragma("unroll") for (int j = 0; j < 4; ++j) {               \
                const int eg = (BASE + j) * 4 + g;                        \
                BS[j] = xb[(size_t)sIdx[w][buf][eg] * 16 + k];            \
                BT[j] = xb[(size_t)tIdx[w][buf][eg] * 16 + k];            \
            }
        #define CONSUME(BS, BT, BASE)                                     \
            _Pragma("unroll") for (int j = 0; j < 4; ++j) {               \
                const int eg = (BASE + j) * 4 + g;                        \
                float d = dot8(BS[j], BT[j]);                             \
                d += __shfl_xor(d, 1);                                    \
                d += __shfl_xor(d, 2);                                    \
                d += __shfl_xor(d, 4);                                    \
                d += __shfl_xor(d, 8);                                    \
                if (k == 0) dotb[w][eg] = d;                              \
            }

        // issue first 16 gathers
        LOADB(sA, tA, 0)
        LOADB(sB, tB, 4)

        // prefetch next burst's indices/attr while gathers are in flight
        long long nxt;
        GRAB(nxt)
        const bool have = nxt < nBursts;
        f32x4 attrNxt = (f32x4)0.f;
        if (have) {
            const long long en = (nxt << 6) + lane;
            int sL = 0, tL = 0;
            if (en < (long long)n_edges) {
                sL = edge_index[en];
                tL = edge_index[(long long)n_edges + en];
                attrNxt = reinterpret_cast<const f32x4*>(edge_attr)[en];
            }
            sIdx[w][buf ^ 1][lane] = sL;
            tIdx[w][buf ^ 1][lane] = tL;
        }

        // consume/issue pipeline
        CONSUME(sA, tA, 0)
        LOADB(sA, tA, 8)
        CONSUME(sB, tB, 4)
        LOADB(sB, tB, 12)
        CONSUME(sA, tA, 8)
        CONSUME(sB, tB, 12)

        #undef LOADB
        #undef CONSUME

        const float cosv = dotb[w][lane];

        // ---- per-lane MLP: feats = {attrCur[0..3], cosv} ----
        float h[H1];
        #pragma unroll
        for (int i = 0; i < H1; ++i) {
            float v = b1[i];
            v = fmaf(attrCur[0], W1[0 * H1 + i], v);
            v = fmaf(attrCur[1], W1[1 * H1 + i], v);
            v = fmaf(attrCur[2], W1[2 * H1 + i], v);
            v = fmaf(attrCur[3], W1[3 * H1 + i], v);
            v = fmaf(cosv,       W1[4 * H1 + i], v);
            h[i] = fmaxf(v, 0.f);
        }

        const f32x4* __restrict__ W2v = reinterpret_cast<const f32x4*>(W2);
        const f32x4* __restrict__ b2v = reinterpret_cast<const f32x4*>(b2);
        if (act) {
            f32x4* op = reinterpret_cast<f32x4*>(out + (size_t)e * H2);
            #pragma unroll
            for (int jg = 0; jg < 8; ++jg) {
                f32x4 a = b2v[jg];
                #pragma unroll
                for (int i = 0; i < H1; ++i)
                    a += h[i] * W2v[i * 8 + jg];
                #pragma unroll
                for (int c = 0; c < 4; ++c)
                    a[c] = fmaxf(a[c], 0.f);
                op[jg] = a;
            }
        }

        if (!have) break;
        cur = nxt;
        attrCur = attrNxt;
        buf ^= 1;
    }
    #undef GRAB
}

// ---------- fallback (fp32 direct, known-good from round 1) ----------
__device__ __forceinline__ float mlp_out32(
    const float4 ea, float cosv,
    const float* __restrict__ sW1, const float* __restrict__ sb1,
    const float* __restrict__ sW2, const float* __restrict__ sb2,
    int sub, int base)
{
    const float f[5] = { ea.x, ea.y, ea.z, ea.w, cosv };
    float hval = 0.f;
    if (sub < H1) {
        hval = sb1[sub];
        #pragma unroll
        for (int kk = 0; kk < 5; ++kk) hval = fmaf(f[kk], sW1[kk * H1 + sub], hval);
        hval = fmaxf(hval, 0.f);
    }
    float acc = sb2[sub];
    #pragma unroll
    for (int i = 0; i < H1; ++i)
        acc = fmaf(__shfl(hval, base + i), sW2[i * H2 + sub], acc);
    return fmaxf(acc, 0.f);
}

__global__ __launch_bounds__(256) void edge_encoder_fp32(
    const float* __restrict__ x,
    const int* __restrict__ edge_index,
    const float* __restrict__ edge_attr,
    const float* __restrict__ W1, const float* __restrict__ b1,
    const float* __restrict__ W2, const float* __restrict__ b2,
    float* __restrict__ out, int n_edges)
{
    __shared__ float sW1[5 * H1];
    __shared__ float sb1[H1];
    __shared__ float sW2[H1 * H2];
    __shared__ float sb2[H2];
    for (int i = threadIdx.x; i < 5 * H1; i += blockDim.x) sW1[i] = W1[i];
    for (int i = threadIdx.x; i < H1; i += blockDim.x) sb1[i] = b1[i];
    for (int i = threadIdx.x; i < H1 * H2; i += blockDim.x) sW2[i] = W2[i];
    for (int i = threadIdx.x; i < H2; i += blockDim.x) sb2[i] = b2[i];
    __syncthreads();

    const int lane = threadIdx.x & 63;
    const int sub = lane & 31;
    const int base = lane & 32;
    const int wavesPerBlock = blockDim.x >> 6;
    const int waveId = blockIdx.x * wavesPerBlock + (threadIdx.x >> 6);
    const int totalWaves = gridDim.x * wavesPerBlock;

    for (long long gg = waveId; 2 * gg < (long long)n_edges; gg += totalWaves) {
        const long long e = 2 * gg + (lane >> 5);
        const bool active = (e < (long long)n_edges);
        float dot = 0.f, ss = 0.f, tt = 0.f;
        float4 ea = make_float4(0.f, 0.f, 0.f, 0.f);
        if (active) {
            const int srcN = edge_index[e];
            const int tgtN = edge_index[(long long)n_edges + e];
            const float4 s4 = *reinterpret_cast<const float4*>(
                x + (size_t)srcN * D_FEAT + (size_t)sub * 4);
            const float4 t4 = *reinterpret_cast<const float4*>(
                x + (size_t)tgtN * D_FEAT + (size_t)sub * 4);
            dot = s4.x * t4.x + s4.y * t4.y + s4.z * t4.z + s4.w * t4.w;
            ss  = s4.x * s4.x + s4.y * s4.y + s4.z * s4.z + s4.w * s4.w;
            tt  = t4.x * t4.x + t4.y * t4.y + t4.z * t4.z + t4.w * t4.w;
            ea = *reinterpret_cast<const float4*>(edge_attr + e * 4);
        }
        #pragma unroll
        for (int m = 16; m >= 1; m >>= 1) {
            dot += __shfl_xor(dot, m);
            ss  += __shfl_xor(ss, m);
            tt  += __shfl_xor(tt, m);
        }
        const float cosv = dot / (fmaxf(sqrtf(ss), EPS) * fmaxf(sqrtf(tt), EPS));
        const float o = mlp_out32(ea, cosv, sW1, sb1, sW2, sb2, sub, base);
        if (active) out[e * H2 + sub] = o;
    }
}

extern "C" void kernel_launch(void* const* d_in, const int* in_sizes, int n_in,
                              void* d_out, int out_size, void* d_ws, size_t ws_size,
                              hipStream_t stream) {
    const float* x         = (const float*)d_in[0];
    const int*   edge_idx  = (const int*)d_in[1];
    const float* edge_attr = (const float*)d_in[2];
    const float* W1        = (const float*)d_in[3];
    const float* b1        = (const float*)d_in[4];
    const float* W2        = (const float*)d_in[5];
    const float* b2        = (const float*)d_in[6];
    float* out = (float*)d_out;

    const int n_nodes = in_sizes[0] / D_FEAT;
    const int n_edges = in_sizes[1] / 2;

    const size_t xb_bytes = (size_t)n_nodes * (D_FEAT / 2) * sizeof(uint32_t);
    const size_t need = xb_bytes + sizeof(unsigned int);

    if (ws_size >= need) {
        uint2* xb = (uint2*)d_ws;
        unsigned int* counter = (unsigned int*)((char*)d_ws + xb_bytes);

        hipMemsetAsync(counter, 0, sizeof(unsigned int), stream);

        const int block = 256;
        const int prep_grid = (n_nodes + 7) / 8;   // 2 nodes/wave, 8/block
        prep_kernel<<<prep_grid, block, 0, stream>>>(x, xb, n_nodes);

        edge_kernel<<<2048, block, 0, stream>>>(
            (const uint4*)xb, edge_idx, edge_attr,
            W1, b1, W2, b2, out, n_edges, counter);
    } else {
        edge_encoder_fp32<<<2048, 256, 0, stream>>>(
            x, edge_idx, edge_attr, W1, b1, W2, b2, out, n_edges);
    }
}

// Round 8
// 84.879 us; speedup vs baseline: 2.8822x; 2.8822x over previous
//
#include <hip/hip_runtime.h>
#include <stdint.h>

#define D_FEAT 128
#define H1 18
#define H2 32
#define EPS 1e-8f

typedef float f32x4 __attribute__((ext_vector_type(4)));

__device__ __forceinline__ uint32_t f32_to_bf16_rne(float f) {
    uint32_t u = __float_as_uint(f);
    return (u + 0x7fffu + ((u >> 16) & 1u)) >> 16;
}
__device__ __forceinline__ float bf16lo(uint32_t v) { return __uint_as_float(v << 16); }
__device__ __forceinline__ float bf16hi(uint32_t v) { return __uint_as_float(v & 0xffff0000u); }

__device__ __forceinline__ float dot8(uint4 s, uint4 t) {
    float d;
    d  = bf16lo(s.x) * bf16lo(t.x);
    d  = fmaf(bf16hi(s.x), bf16hi(t.x), d);
    d  = fmaf(bf16lo(s.y), bf16lo(t.y), d);
    d  = fmaf(bf16hi(s.y), bf16hi(t.y), d);
    d  = fmaf(bf16lo(s.z), bf16lo(t.z), d);
    d  = fmaf(bf16hi(s.z), bf16hi(t.z), d);
    d  = fmaf(bf16lo(s.w), bf16lo(t.w), d);
    d  = fmaf(bf16hi(s.w), bf16hi(t.w), d);
    return d;
}

// ---------- prep: x[f32,N,128] -> NORMALIZED packed bf16 [N,32 uint2] ----------
// nt load on x only: streamed exactly once, keep it from evicting xb.
__global__ __launch_bounds__(256) void prep_kernel(
    const float* __restrict__ x,
    uint2* __restrict__ xb,
    int n_nodes)
{
    const int lane = threadIdx.x & 63;
    const int sub = lane & 31;
    const int half = lane >> 5;
    const int wavesPerBlock = blockDim.x >> 6;
    const long long wv = (long long)blockIdx.x * wavesPerBlock + (threadIdx.x >> 6);
    const int node = (int)(2 * wv + half);
    if (node >= n_nodes) return;

    const f32x4 v = __builtin_nontemporal_load(
        reinterpret_cast<const f32x4*>(x + (size_t)node * D_FEAT) + sub);
    float ss = v[0] * v[0] + v[1] * v[1] + v[2] * v[2] + v[3] * v[3];
    #pragma unroll
    for (int m = 16; m >= 1; m >>= 1) ss += __shfl_xor(ss, m);
    const float r = 1.0f / fmaxf(sqrtf(ss), EPS);
    uint2 p;
    p.x = (f32_to_bf16_rne(v[1] * r) << 16) | f32_to_bf16_rne(v[0] * r);
    p.y = (f32_to_bf16_rne(v[3] * r) << 16) | f32_to_bf16_rne(v[2] * r);
    xb[(size_t)node * 32 + sub] = p;
}

// ---------- main: static 2 bursts per wave, cross-burst pipelining ----------
__global__ __launch_bounds__(256) void edge_kernel(
    const uint4* __restrict__ xb,       // [N][16] (8 bf16 per uint4)
    const int* __restrict__ edge_index, // [2, E]
    const float* __restrict__ edge_attr,
    const float* __restrict__ W1, const float* __restrict__ b1,
    const float* __restrict__ W2, const float* __restrict__ b2,
    float* __restrict__ out, int n_edges)
{
    __shared__ int sIdx[4][2][64];
    __shared__ int tIdx[4][2][64];
    __shared__ float dotb[4][64];

    const int lane = threadIdx.x & 63;
    const int w = threadIdx.x >> 6;
    const int g = lane >> 4;
    const int k = lane & 15;
    const long long nBursts = ((long long)n_edges + 63) >> 6;
    const long long waveId = (long long)blockIdx.x * 4 + w;
    const long long bu0 = waveId * 2;
    const long long bu1 = bu0 + 1;
    if (bu0 >= nBursts) return;
    const bool have1 = bu1 < nBursts;

    const f32x4* __restrict__ eav = reinterpret_cast<const f32x4*>(edge_attr);
    const f32x4* __restrict__ W2v = reinterpret_cast<const f32x4*>(W2);
    const f32x4* __restrict__ b2v = reinterpret_cast<const f32x4*>(b2);

    // ---- stage burst0 indices + attr ----
    const long long e0 = (bu0 << 6) + lane;
    const bool act0 = e0 < (long long)n_edges;
    f32x4 attr0 = (f32x4)0.f;
    {
        int sL = 0, tL = 0;
        if (act0) {
            sL = edge_index[e0];
            tL = edge_index[(long long)n_edges + e0];
            attr0 = eav[e0];
        }
        sIdx[w][0][lane] = sL;
        tIdx[w][0][lane] = tL;
    }

    uint4 sA[4], tA[4], sB[4], tB[4];

    #define LOADB(BS, BT, BASE, BUF)                                      \
        _Pragma("unroll") for (int j = 0; j < 4; ++j) {                   \
            const int eg = (BASE + j) * 4 + g;                            \
            BS[j] = xb[(size_t)sIdx[w][BUF][eg] * 16 + k];                \
            BT[j] = xb[(size_t)tIdx[w][BUF][eg] * 16 + k];                \
        }
    #define CONSUME(BS, BT, BASE)                                         \
        _Pragma("unroll") for (int j = 0; j < 4; ++j) {                   \
            const int eg = (BASE + j) * 4 + g;                            \
            float d = dot8(BS[j], BT[j]);                                 \
            d += __shfl_xor(d, 1);                                        \
            d += __shfl_xor(d, 2);                                        \
            d += __shfl_xor(d, 4);                                        \
            d += __shfl_xor(d, 8);                                        \
            if (k == 0) dotb[w][eg] = d;                                  \
        }
    #define MLP_STORE(ATTR, ACT, E)                                       \
        {                                                                 \
            const float cosv = dotb[w][lane];                             \
            float h[H1];                                                  \
            _Pragma("unroll") for (int i = 0; i < H1; ++i) {              \
                float v = b1[i];                                          \
                v = fmaf(ATTR[0], W1[0 * H1 + i], v);                     \
                v = fmaf(ATTR[1], W1[1 * H1 + i], v);                     \
                v = fmaf(ATTR[2], W1[2 * H1 + i], v);                     \
                v = fmaf(ATTR[3], W1[3 * H1 + i], v);                     \
                v = fmaf(cosv,    W1[4 * H1 + i], v);                     \
                h[i] = fmaxf(v, 0.f);                                     \
            }                                                             \
            if (ACT) {                                                    \
                f32x4* op = reinterpret_cast<f32x4*>(out + (size_t)(E) * H2); \
                _Pragma("unroll") for (int jg = 0; jg < 8; ++jg) {        \
                    f32x4 a = b2v[jg];                                    \
                    _Pragma("unroll") for (int i = 0; i < H1; ++i)        \
                        a += h[i] * W2v[i * 8 + jg];                      \
                    _Pragma("unroll") for (int c = 0; c < 4; ++c)         \
                        a[c] = fmaxf(a[c], 0.f);                          \
                    op[jg] = a;                                           \
                }                                                         \
            }                                                             \
        }

    // ---- burst0: issue first 16 gathers ----
    LOADB(sA, tA, 0, 0)
    LOADB(sB, tB, 4, 0)

    // ---- prefetch burst1 indices + attr while gathers are in flight ----
    const long long e1 = (bu1 << 6) + lane;
    const bool act1 = have1 && (e1 < (long long)n_edges);
    f32x4 attr1 = (f32x4)0.f;
    if (have1) {
        int sL = 0, tL = 0;
        if (act1) {
            sL = edge_index[e1];
            tL = edge_index[(long long)n_edges + e1];
            attr1 = eav[e1];
        }
        sIdx[w][1][lane] = sL;
        tIdx[w][1][lane] = tL;
    }

    // ---- burst0: consume/issue pipeline ----
    CONSUME(sA, tA, 0)
    LOADB(sA, tA, 8, 0)
    CONSUME(sB, tB, 4)
    LOADB(sB, tB, 12, 0)
    CONSUME(sA, tA, 8)
    CONSUME(sB, tB, 12)

    // ---- burst1: issue first 16 gathers BEFORE burst0's MLP ----
    if (have1) {
        LOADB(sA, tA, 0, 1)
        LOADB(sB, tB, 4, 1)
    }

    // ---- burst0 MLP + store (hides burst1 gather latency) ----
    MLP_STORE(attr0, act0, e0)

    if (!have1) return;

    // ---- burst1: finish pipeline ----
    CONSUME(sA, tA, 0)
    LOADB(sA, tA, 8, 1)
    CONSUME(sB, tB, 4)
    LOADB(sB, tB, 12, 1)
    CONSUME(sA, tA, 8)
    CONSUME(sB, tB, 12)

    MLP_STORE(attr1, act1, e1)

    #undef LOADB
    #undef CONSUME
    #undef MLP_STORE
}

// ---------- fallback (fp32 direct, known-good from round 1) ----------
__device__ __forceinline__ float mlp_out32(
    const float4 ea, float cosv,
    const float* __restrict__ sW1, const float* __restrict__ sb1,
    const float* __restrict__ sW2, const float* __restrict__ sb2,
    int sub, int base)
{
    const float f[5] = { ea.x, ea.y, ea.z, ea.w, cosv };
    float hval = 0.f;
    if (sub < H1) {
        hval = sb1[sub];
        #pragma unroll
        for (int kk = 0; kk < 5; ++kk) hval = fmaf(f[kk], sW1[kk * H1 + sub], hval);
        hval = fmaxf(hval, 0.f);
    }
    float acc = sb2[sub];
    #pragma unroll
    for (int i = 0; i < H1; ++i)
        acc = fmaf(__shfl(hval, base + i), sW2[i * H2 + sub], acc);
    return fmaxf(acc, 0.f);
}

__global__ __launch_bounds__(256) void edge_encoder_fp32(
    const float* __restrict__ x,
    const int* __restrict__ edge_index,
    const float* __restrict__ edge_attr,
    const float* __restrict__ W1, const float* __restrict__ b1,
    const float* __restrict__ W2, const float* __restrict__ b2,
    float* __restrict__ out, int n_edges)
{
    __shared__ float sW1[5 * H1];
    __shared__ float sb1[H1];
    __shared__ float sW2[H1 * H2];
    __shared__ float sb2[H2];
    for (int i = threadIdx.x; i < 5 * H1; i += blockDim.x) sW1[i] = W1[i];
    for (int i = threadIdx.x; i < H1; i += blockDim.x) sb1[i] = b1[i];
    for (int i = threadIdx.x; i < H1 * H2; i += blockDim.x) sW2[i] = W2[i];
    for (int i = threadIdx.x; i < H2; i += blockDim.x) sb2[i] = b2[i];
    __syncthreads();

    const int lane = threadIdx.x & 63;
    const int sub = lane & 31;
    const int base = lane & 32;
    const int wavesPerBlock = blockDim.x >> 6;
    const int waveId = blockIdx.x * wavesPerBlock + (threadIdx.x >> 6);
    const int totalWaves = gridDim.x * wavesPerBlock;

    for (long long gg = waveId; 2 * gg < (long long)n_edges; gg += totalWaves) {
        const long long e = 2 * gg + (lane >> 5);
        const bool active = (e < (long long)n_edges);
        float dot = 0.f, ss = 0.f, tt = 0.f;
        float4 ea = make_float4(0.f, 0.f, 0.f, 0.f);
        if (active) {
            const int srcN = edge_index[e];
            const int tgtN = edge_index[(long long)n_edges + e];
            const float4 s4 = *reinterpret_cast<const float4*>(
                x + (size_t)srcN * D_FEAT + (size_t)sub * 4);
            const float4 t4 = *reinterpret_cast<const float4*>(
                x + (size_t)tgtN * D_FEAT + (size_t)sub * 4);
            dot = s4.x * t4.x + s4.y * t4.y + s4.z * t4.z + s4.w * t4.w;
            ss  = s4.x * s4.x + s4.y * s4.y + s4.z * s4.z + s4.w * s4.w;
            tt  = t4.x * t4.x + t4.y * t4.y + t4.z * t4.z + t4.w * t4.w;
            ea = *reinterpret_cast<const float4*>(edge_attr + e * 4);
        }
        #pragma unroll
        for (int m = 16; m >= 1; m >>= 1) {
            dot += __shfl_xor(dot, m);
            ss  += __shfl_xor(ss, m);
            tt  += __shfl_xor(tt, m);
        }
        const float cosv = dot / (fmaxf(sqrtf(ss), EPS) * fmaxf(sqrtf(tt), EPS));
        const float o = mlp_out32(ea, cosv, sW1, sb1, sW2, sb2, sub, base);
        if (active) out[e * H2 + sub] = o;
    }
}

extern "C" void kernel_launch(void* const* d_in, const int* in_sizes, int n_in,
                              void* d_out, int out_size, void* d_ws, size_t ws_size,
                              hipStream_t stream) {
    const float* x         = (const float*)d_in[0];
    const int*   edge_idx  = (const int*)d_in[1];
    const float* edge_attr = (const float*)d_in[2];
    const float* W1        = (const float*)d_in[3];
    const float* b1        = (const float*)d_in[4];
    const float* W2        = (const float*)d_in[5];
    const float* b2        = (const float*)d_in[6];
    float* out = (float*)d_out;

    const int n_nodes = in_sizes[0] / D_FEAT;
    const int n_edges = in_sizes[1] / 2;

    const size_t xb_bytes = (size_t)n_nodes * (D_FEAT / 2) * sizeof(uint32_t);

    if (ws_size >= xb_bytes) {
        uint2* xb = (uint2*)d_ws;
        const int block = 256;
        const int prep_grid = (n_nodes + 7) / 8;   // 2 nodes/wave, 8/block
        prep_kernel<<<prep_grid, block, 0, stream>>>(x, xb, n_nodes);

        const long long nBursts = ((long long)n_edges + 63) >> 6;
        const long long nWaves = (nBursts + 1) / 2;   // exactly 2 bursts/wave
        const int grid = (int)((nWaves + 3) / 4);
        edge_kernel<<<grid, block, 0, stream>>>(
            (const uint4*)xb, edge_idx, edge_attr,
            W1, b1, W2, b2, out, n_edges);
    } else {
        edge_encoder_fp32<<<2048, 256, 0, stream>>>(
            x, edge_idx, edge_attr, W1, b1, W2, b2, out, n_edges);
    }
}